// Round 9
// baseline (157.662 us; speedup 1.0000x reference)
//
#include <hip/hip_runtime.h>
#include <hip/hip_bf16.h>
#include <math.h>

#define NCC 64
#define CSC 64
#define DC 64
#define S 72            // bf16 LDS row stride (144 B rows)
#define EPSF 1e-6f
#define LDS_BYTES 65536

typedef __attribute__((ext_vector_type(8)))  short bf16x8;  // MFMA A/B frag
typedef __attribute__((ext_vector_type(4)))  float f32x4;   // 16x16 C/D frag
typedef __attribute__((ext_vector_type(16))) float f32x16;  // 32x32 C/D frag
typedef __attribute__((ext_vector_type(4)))  short short4v;

static __device__ __forceinline__ short cvt_bf16(float x) { // HW RNE
    union { __hip_bfloat16 b; short s; } u;
    u.b = __float2bfloat16(x);
    return u.s;
}

// 16-lane sum via DPP row rotations (VALU-only; DPP row = 16 lanes).
#define DPP_ROR_ADD(v, N)                                                     \
    do {                                                                      \
        union { float f; int i; } _u, _r;                                     \
        _u.f = (v);                                                           \
        _r.i = __builtin_amdgcn_mov_dpp(_u.i, 0x120 + (N), 0xF, 0xF, true);   \
        (v) += _r.f;                                                          \
    } while (0)

static __device__ __forceinline__ float red16(float v) {
    DPP_ROR_ADD(v, 1);
    DPP_ROR_ADD(v, 2);
    DPP_ROR_ADD(v, 4);
    DPP_ROR_ADD(v, 8);
    return v;
}

__global__ __launch_bounds__(512, 1) void ttt_kernel(
    const float* __restrict__ xk, const float* __restrict__ xv,
    const float* __restrict__ weight, const float* __restrict__ bias,
    const float* __restrict__ gamma, const float* __restrict__ beta,
    const float* __restrict__ theta, const float* __restrict__ theta_bias,
    const float* __restrict__ alpha, float* __restrict__ out)
{
    extern __shared__ char sb[];
    auto xs_rm = (short (*)[CSC][S])(sb);             // [2][64][S] xk row-major [k][d]
    auto xsT   = (short (*)[DC][S]) (sb + 18432);     // [2][64][S] xk^T [d][k]
    auto gsT   = (short (*)[S])     (sb + 36864);     // gs^T [e][k]
    auto Gr    = (short (*)[S])     (sb + 46080);     // Gram+1 [j'][j] (symmetric)
    auto Wtb   = (short (*)[S])     (sb + 55296);     // W [e][d]
    auto dbp   = (float (*)[DC])    (sb + 64512);     // [4][64] db partials

    const int t   = threadIdx.x;
    const int w   = t >> 6;           // wave 0..7
    const bool lo = (w < 4);          // lo: z16+epilogue+dW+staging, hi: z32+Gram+out
    const int ws  = w & 3;
    const int l   = t & 63;
    const int g   = l >> 4, la = l & 15;      // 16-style
    const int la5 = l & 31, hi5 = l >> 5;     // 32-style
    const int R   = ws >> 1, E = ws & 1;      // 32x32 tile coords
    const int r0  = 16*ws + 4*g;              // lo: epilogue rows r0..r0+3
    const int ts  = 64*ws + l;                // lo: staging thread id 0..255
    const int bh  = blockIdx.x;
    const int h   = bh & 15;

    const size_t bh_off = (size_t)bh * NCC*CSC*DC;
    const float* xkb = xk + bh_off;
    const float* xvb = xv + bh_off;
    float*       ob  = out + bh_off;

    // lo state
    float gam[4], bet[4], thv[4], tok[4], bcol[4], tb = 0.f;
    float Wreg[16];                   // W state, 32x32 C-frag layout, tile (R,E)
    float4 xl[4];
    float xkh[4][4], xkE[4][4], xvg[4][4], xvN[4][4];
    // hi state
    float bcolh = 0.f;
    f32x16 z32;

    if (lo) {
#pragma unroll
        for (int n = 0; n < 4; ++n) {
            gam[n]  = gamma[h*DC + 16*n + la];
            bet[n]  = beta [h*DC + 16*n + la];
            thv[n]  = theta[h*DC + 16*n + la];
            bcol[n] = bias [h*DC + 16*n + la];
        }
        tb = theta_bias[h];
#pragma unroll
        for (int i = 0; i < 4; ++i)
            tok[i] = fmaxf(1.0f/(float)(r0+i+1) + alpha[r0+i], 0.0f);
        const float* wg = weight + h*DC*DC;
#pragma unroll
        for (int q = 0; q < 4; ++q) {
            short4v sw;
#pragma unroll
            for (int j = 0; j < 4; ++j) {
                Wreg[4*q+j] = wg[(32*R + 8*q + 4*hi5 + j)*DC + 32*E + la5];
                sw[j] = cvt_bf16(Wreg[4*q+j]);
            }
            *(short4v*)&Wtb[32*E + la5][32*R + 8*q + 4*hi5] = sw;
        }
#pragma unroll
        for (int i4 = 0; i4 < 4; ++i4) xl[i4] = ((const float4*)xkb)[ts + 256*i4];
#pragma unroll
        for (int i = 0; i < 4; ++i)
#pragma unroll
            for (int n = 0; n < 4; ++n) {
                xkh[i][n] = xkb[(r0+i)*DC + 16*n + la];
                xvg[i][n] = xvb[(r0+i)*DC + 16*n + la];
                xkE[i][n] = xkh[i][n];
            }
#pragma unroll
        for (int i4 = 0; i4 < 4; ++i4) {      // stage chunk 0 row-major
            int f = ts + 256*i4, k = f >> 4, j = f & 15;
            short4v s4;
            s4[0]=cvt_bf16(xl[i4].x); s4[1]=cvt_bf16(xl[i4].y);
            s4[2]=cvt_bf16(xl[i4].z); s4[3]=cvt_bf16(xl[i4].w);
            *(short4v*)&xs_rm[0][k][4*j] = s4;
        }
#pragma unroll
        for (int n = 0; n < 4; ++n) {         // stage chunk 0 transposed
            short4v sv;
#pragma unroll
            for (int i = 0; i < 4; ++i) sv[i] = cvt_bf16(xkh[i][n]);
            *(short4v*)&xsT[0][16*n + la][r0] = sv;
        }
    } else {
        bcolh = bias[h*DC + 32*E + la5];
    }
    __syncthreads();

    for (int c = 0; c < NCC; ++c) {
        const int cb = c & 1, nb = cb ^ 1;
        const bool pf = (c + 1 < NCC);

        if (lo) {
            // ---- P1-lo: z16 + 4-row epilogue -> gsT/dbp ----
            const bf16x8 a0 = *(const bf16x8*)&xs_rm[cb][16*ws + la][8*g];
            const bf16x8 a1 = *(const bf16x8*)&xs_rm[cb][16*ws + la][32 + 8*g];
            f32x4 zt[4];
#pragma unroll
            for (int n = 0; n < 4; ++n) {
                bf16x8 w0 = *(const bf16x8*)&Wtb[16*n + la][8*g];
                bf16x8 w1 = *(const bf16x8*)&Wtb[16*n + la][32 + 8*g];
                f32x4 zz = {0.f,0.f,0.f,0.f};
                zz = __builtin_amdgcn_mfma_f32_16x16x32_bf16(a0, w0, zz, 0,0,0);
                zz = __builtin_amdgcn_mfma_f32_16x16x32_bf16(a1, w1, zz, 0,0,0);
                zt[n] = zz;
            }
            // prefetch next chunk's VMEM (overlaps epilogue)
            if (pf) {
                const float* xkn = xkb + (c+1)*CSC*DC;
                const float* xvn = xvb + (c+1)*CSC*DC;
#pragma unroll
                for (int i4 = 0; i4 < 4; ++i4) xl[i4] = ((const float4*)xkn)[ts + 256*i4];
#pragma unroll
                for (int i = 0; i < 4; ++i)
#pragma unroll
                    for (int n = 0; n < 4; ++n) {
                        xkh[i][n] = xkn[(r0+i)*DC + 16*n + la];
                        xvN[i][n] = xvn[(r0+i)*DC + 16*n + la];
                    }
            }
            // epilogue: 4 rows/thread, fp32, DPP reductions
            float gsv[4][4];
#pragma unroll
            for (int i = 0; i < 4; ++i) {
                float z0 = zt[0][i]+bcol[0], z1 = zt[1][i]+bcol[1];
                float z2 = zt[2][i]+bcol[2], z3 = zt[3][i]+bcol[3];
                float szz = red16(z0*z0 + z1*z1 + z2*z2 + z3*z3);
                float sz  = red16(z0 + z1 + z2 + z3);
                float thd = red16(xkE[i][0]*thv[0] + xkE[i][1]*thv[1] +
                                  xkE[i][2]*thv[2] + xkE[i][3]*thv[3]);
                float mu   = sz * (1.0f/DC);
                float var  = szz*(1.0f/DC) - mu*mu;
                float rstd = rsqrtf(var + EPSF);
                float ex   = __expf(-(thd + tb));
                float lr   = __builtin_amdgcn_rcpf(1.0f + ex);
                float eta  = tok[i]*lr*(1.0f/DC);
                float zz4[4] = {z0,z1,z2,z3};
                float xh[4], gxh[4], a1v = 0.f, a2v = 0.f;
#pragma unroll
                for (int n = 0; n < 4; ++n) {
                    xh[n] = (zz4[n]-mu)*rstd;
                    float y  = fmaf(gam[n], xh[n], bet[n]);
                    float go = y - xvg[i][n] + xkE[i][n];
                    gxh[n] = go*gam[n];
                    a1v += gxh[n];
                    a2v = fmaf(gxh[n], xh[n], a2v);
                }
                float s1 = red16(a1v), s2 = red16(a2v);
                float sc = rstd*(1.0f/DC)*eta;
#pragma unroll
                for (int n = 0; n < 4; ++n)
                    gsv[i][n] = (64.f*gxh[n] - s1 - xh[n]*s2)*sc;
            }
#pragma unroll
            for (int n = 0; n < 4; ++n) {     // gsT b64 packs
                short4v sg;
#pragma unroll
                for (int i = 0; i < 4; ++i) sg[i] = cvt_bf16(gsv[i][n]);
                *(short4v*)&gsT[16*n + la][r0] = sg;
            }
            float dbl[4];
#pragma unroll
            for (int n = 0; n < 4; ++n) {
                float dd = gsv[0][n]+gsv[1][n]+gsv[2][n]+gsv[3][n];
                dd += __shfl_xor(dd, 16);
                dd += __shfl_xor(dd, 32);
                dbl[n] = dd;
            }
            if (l < 16) {
                f32x4 dv = {dbl[0], dbl[1], dbl[2], dbl[3]};
                *(f32x4*)&dbp[ws][4*la] = dv;
            }
        } else {
            // ---- P1-hi: z32 + Gram32 (tile (R,E)) ----
            bf16x8 az[4], bz[4];
#pragma unroll
            for (int s = 0; s < 4; ++s) {
                az[s] = *(const bf16x8*)&xs_rm[cb][32*R + la5][16*s + 8*hi5];
                bz[s] = *(const bf16x8*)&Wtb[32*E + la5][16*s + 8*hi5];
            }
            f32x16 zz = {0.f,0.f,0.f,0.f,0.f,0.f,0.f,0.f,
                         0.f,0.f,0.f,0.f,0.f,0.f,0.f,0.f};
#pragma unroll
            for (int s = 0; s < 4; ++s)
                zz = __builtin_amdgcn_mfma_f32_32x32x16_bf16(az[s], bz[s], zz, 0,0,0);
            z32 = zz;
            bf16x8 bg[4];
            if (R == E) {
#pragma unroll
                for (int s = 0; s < 4; ++s) bg[s] = az[s];
            } else {
#pragma unroll
                for (int s = 0; s < 4; ++s)
                    bg[s] = *(const bf16x8*)&xs_rm[cb][32*E + la5][16*s + 8*hi5];
            }
            f32x16 gg = {0.f,0.f,0.f,0.f,0.f,0.f,0.f,0.f,
                         0.f,0.f,0.f,0.f,0.f,0.f,0.f,0.f};
#pragma unroll
            for (int s = 0; s < 4; ++s)
                gg = __builtin_amdgcn_mfma_f32_32x32x16_bf16(az[s], bg[s], gg, 0,0,0);
#pragma unroll
            for (int q = 0; q < 4; ++q) {     // Gr = Gram + 1 (ones-trick), via symmetry
                short4v sg;
#pragma unroll
                for (int j = 0; j < 4; ++j) sg[j] = cvt_bf16(gg[4*q+j] + 1.0f);
                *(short4v*)&Gr[32*E + la5][32*R + 8*q + 4*hi5] = sg;
            }
        }
        __syncthreads();    // B: gsT, dbp, Gr ready

        if (lo) {
            // ---- P2-lo: dW32 + W update + staging + bias ----
            bf16x8 ax[4], bx[4];
#pragma unroll
            for (int s = 0; s < 4; ++s) {
                ax[s] = *(const bf16x8*)&xsT[cb][32*R + la5][16*s + 8*hi5];
                bx[s] = *(const bf16x8*)&gsT[32*E + la5][16*s + 8*hi5];
            }
            f32x16 dw = {0.f,0.f,0.f,0.f,0.f,0.f,0.f,0.f,
                         0.f,0.f,0.f,0.f,0.f,0.f,0.f,0.f};
#pragma unroll
            for (int s = 0; s < 4; ++s)
                dw = __builtin_amdgcn_mfma_f32_32x32x16_bf16(ax[s], bx[s], dw, 0,0,0);
#pragma unroll
            for (int q = 0; q < 4; ++q) {
                short4v sw;
#pragma unroll
                for (int j = 0; j < 4; ++j) {
                    Wreg[4*q+j] -= dw[4*q+j];
                    sw[j] = cvt_bf16(Wreg[4*q+j]);
                }
                *(short4v*)&Wtb[32*E + la5][32*R + 8*q + 4*hi5] = sw;
            }
            if (pf) {                         // stage chunk c+1
#pragma unroll
                for (int i4 = 0; i4 < 4; ++i4) {
                    int f = ts + 256*i4, k = f >> 4, j = f & 15;
                    short4v s4;
                    s4[0]=cvt_bf16(xl[i4].x); s4[1]=cvt_bf16(xl[i4].y);
                    s4[2]=cvt_bf16(xl[i4].z); s4[3]=cvt_bf16(xl[i4].w);
                    *(short4v*)&xs_rm[nb][k][4*j] = s4;
                }
#pragma unroll
                for (int n = 0; n < 4; ++n) {
                    short4v sv;
#pragma unroll
                    for (int i = 0; i < 4; ++i) sv[i] = cvt_bf16(xkh[i][n]);
                    *(short4v*)&xsT[nb][16*n + la][r0] = sv;
                }
#pragma unroll
                for (int i = 0; i < 4; ++i)
#pragma unroll
                    for (int n = 0; n < 4; ++n) {
                        xkE[i][n] = xkh[i][n];
                        xvg[i][n] = xvN[i][n];
                    }
            }
            {   // bias state update (fixed order; identical to hi's scalar order)
                f32x4 s = *(const f32x4*)&dbp[0][4*la];
#pragma unroll
                for (int p = 1; p < 4; ++p) {
                    f32x4 d = *(const f32x4*)&dbp[p][4*la];
#pragma unroll
                    for (int n = 0; n < 4; ++n) s[n] += d[n];
                }
#pragma unroll
                for (int n = 0; n < 4; ++n) bcol[n] -= s[n];
            }
        } else {
            // ---- P2-hi: out32 = z32 - (Gram+1)@gs + b_old ----
            bf16x8 ag[4], bq[4];
#pragma unroll
            for (int s = 0; s < 4; ++s) {
                ag[s] = *(const bf16x8*)&Gr[32*R + la5][16*s + 8*hi5];
                bq[s] = *(const bf16x8*)&gsT[32*E + la5][16*s + 8*hi5];
            }
            f32x16 og = {0.f,0.f,0.f,0.f,0.f,0.f,0.f,0.f,
                         0.f,0.f,0.f,0.f,0.f,0.f,0.f,0.f};
#pragma unroll
            for (int s = 0; s < 4; ++s)
                og = __builtin_amdgcn_mfma_f32_32x32x16_bf16(ag[s], bq[s], og, 0,0,0);
            float* oc = ob + c*CSC*DC;
#pragma unroll
            for (int q = 0; q < 4; ++q)
#pragma unroll
                for (int j = 0; j < 4; ++j) {
                    int r = 4*q + j;
                    oc[(32*R + 8*q + 4*hi5 + j)*DC + 32*E + la5] =
                        z32[r] - og[r] + bcolh;
                }
            {   // bias state update (after using b_old; same add order as lo)
                int idx = 4*(la5 & 15) + 2*E + (la5 >> 4);
                float s0 = dbp[0][idx];
                s0 += dbp[1][idx];
                s0 += dbp[2][idx];
                s0 += dbp[3][idx];
                bcolh -= s0;
            }
        }
        __syncthreads();    // C: Wtb + staged next-chunk buffers ready
    }
}

extern "C" void kernel_launch(void* const* d_in, const int* in_sizes, int n_in,
                              void* d_out, int out_size, void* d_ws, size_t ws_size,
                              hipStream_t stream) {
    const float* xk         = (const float*)d_in[0];
    const float* xv         = (const float*)d_in[1];
    const float* weight     = (const float*)d_in[2];
    const float* bias       = (const float*)d_in[3];
    const float* gamma      = (const float*)d_in[4];
    const float* beta       = (const float*)d_in[5];
    const float* theta      = (const float*)d_in[6];
    const float* theta_bias = (const float*)d_in[7];
    const float* alpha      = (const float*)d_in[8];
    float* out = (float*)d_out;

    (void)hipFuncSetAttribute((const void*)ttt_kernel,
                              hipFuncAttributeMaxDynamicSharedMemorySize,
                              LDS_BYTES);
    ttt_kernel<<<64, 512, LDS_BYTES, stream>>>(xk, xv, weight, bias, gamma, beta,
                                               theta, theta_bias, alpha, out);
}